// Round 2
// baseline (111.657 us; speedup 1.0000x reference)
//
#include <hip/hip_runtime.h>

#define BB 8
#define NN 128
#define CC 32

struct Params {
  const float* atom0; const float* atom1; const float* atom2;
  const float* edge0; const float* edge1; const float* edge2;
  const void*  mask;   // dtype probed at runtime: int32 / bool-byte / float32
  const float* cg[14];
  const float* w0; const float* w1; const float* w2;
  float* out;
};

// O accumulator layout (81 floats):
// O00:0, O01:1..3, O02:4..8, O10:9..11, O11:12..20, O12:21..35,
// O20:36..40, O21:41..55, O22:56..80

__global__ __launch_bounds__(256) void lgn_kernel(Params p) {
  const int tid = threadIdx.x;
  const int c   = tid & 31;   // channel
  const int g   = tid >> 5;   // j-group 0..7
  const int blk = blockIdx.x;
  const int b   = blk & 7;    // XCD-friendly: same b stays on same XCD
  const int i   = blk >> 3;

  __shared__ float sm_red[2 * 32 * 81]; // 5184 floats (reused as mixp later)
  __shared__ float sm_cat[3360];
  __shared__ float sm_cg[540];
  __shared__ float sm_ai[288];          // node-i atoms: [c][9]
  __shared__ unsigned char sm_mask[NN];
  __shared__ int sm_mode;

  // ---------------- probe mask dtype (block-uniform) ----------------
  if (tid == 0) sm_mode = 0;
  __syncthreads();
  if (tid < 64) {
    unsigned v = ((const unsigned*)p.mask)[tid];
    if (v == 0x3F800000u) atomicOr(&sm_mode, 2);       // float32 storage
    else if (v > 1u)      atomicOr(&sm_mode, 1);       // packed byte storage
  }
  __syncthreads();
  const int mode = (sm_mode & 2) ? 2 : sm_mode;        // 0=int32, 1=byte, 2=float

  // ---------------- stage mask row, cg, node-i atoms into LDS ----------------
  if (tid < NN) {
    const int midx = (b * NN + i) * NN + tid;
    bool mv;
    if (mode == 0)      mv = ((const int*)p.mask)[midx] != 0;
    else if (mode == 2) mv = ((const float*)p.mask)[midx] != 0.f;
    else                mv = ((const unsigned char*)p.mask)[midx] != 0;
    sm_mask[tid] = mv ? 1 : 0;
  }
  {
    constexpr int CGSZ[14] = {1,9,25, 9,9,27,45,45, 25,45,75,25,75,125};
    constexpr int CGOF[14] = {0,1,10, 35,44,53,80,125, 170,195,240,315,340,415};
    #pragma unroll
    for (int tnum = 0; tnum < 14; ++tnum)
      for (int idx = tid; idx < CGSZ[tnum]; idx += 256)
        sm_cg[CGOF[tnum] + idx] = p.cg[tnum][idx];
    const int nodeBase = (b * NN + i) * CC;
    for (int s2 = tid; s2 < 288; s2 += 256) {
      int cc = s2 / 9, comp = s2 - cc * 9;
      float v;
      if (comp == 0)      v = p.atom0[nodeBase + cc];
      else if (comp < 4)  v = p.atom1[(nodeBase + cc) * 3 + comp - 1];
      else                v = p.atom2[(nodeBase + cc) * 5 + comp - 4];
      sm_ai[s2] = v;
    }
  }
  __syncthreads();

  // ---------------- main masked neighbor loop ----------------
  float O[81];
  #pragma unroll
  for (int q = 0; q < 81; ++q) O[q] = 0.f;

  const float* a0b = p.atom0 +  b * NN * CC + c;
  const float* a1b = p.atom1 + (b * NN * CC + c) * 3;
  const float* a2b = p.atom2 + (b * NN * CC + c) * 5;
  const float* e0b = p.edge0 +  ((b * NN + i) * NN) * CC + c;
  const float* e1b = p.edge1 + (((b * NN + i) * NN) * CC + c) * 3;
  const float* e2b = p.edge2 + (((b * NN + i) * NN) * CC + c) * 5;

  for (int t = 0; t < 16; ++t) {
    const int j = g + (t << 3);  // wave halves get adjacent j -> contiguous spans
    if (sm_mask[j]) {            // mask==0: skip loads entirely
      const float* a1p = a1b + j * CC * 3;
      const float* a2p = a2b + j * CC * 5;
      const float* e1p = e1b + j * CC * 3;
      const float* e2p = e2b + j * CC * 5;
      float a0 = a0b[j * CC];
      float e0 = e0b[j * CC];
      float a1v[3], e1v[3], a2v[5], e2v[5];
      #pragma unroll
      for (int x = 0; x < 3; ++x) { a1v[x] = a1p[x]; e1v[x] = e1p[x]; }
      #pragma unroll
      for (int x = 0; x < 5; ++x) { a2v[x] = a2p[x]; e2v[x] = e2p[x]; }

      O[0] += a0 * e0;
      #pragma unroll
      for (int y = 0; y < 3; ++y) O[1 + y] += a0 * e1v[y];
      #pragma unroll
      for (int y = 0; y < 5; ++y) O[4 + y] += a0 * e2v[y];
      #pragma unroll
      for (int x = 0; x < 3; ++x) O[9 + x] += a1v[x] * e0;
      #pragma unroll
      for (int x = 0; x < 3; ++x)
        #pragma unroll
        for (int y = 0; y < 3; ++y) O[12 + x * 3 + y] += a1v[x] * e1v[y];
      #pragma unroll
      for (int x = 0; x < 3; ++x)
        #pragma unroll
        for (int y = 0; y < 5; ++y) O[21 + x * 5 + y] += a1v[x] * e2v[y];
      #pragma unroll
      for (int x = 0; x < 5; ++x) O[36 + x] += a2v[x] * e0;
      #pragma unroll
      for (int x = 0; x < 5; ++x)
        #pragma unroll
        for (int y = 0; y < 3; ++y) O[41 + x * 3 + y] += a2v[x] * e1v[y];
      #pragma unroll
      for (int x = 0; x < 5; ++x)
        #pragma unroll
        for (int y = 0; y < 5; ++y) O[56 + x * 5 + y] += a2v[x] * e2v[y];
    }
  }

  // ---------------- reduce 8 j-group partials ----------------
  #pragma unroll
  for (int q = 0; q < 81; ++q) O[q] += __shfl_down(O[q], 32);

  const int wave = tid >> 6;
  const int lane = tid & 63;
  if (lane < 32 && wave < 2) {
    #pragma unroll
    for (int q = 0; q < 81; ++q) sm_red[(wave * 32 + c) * 81 + q] = O[q];
  }
  __syncthreads();
  if (lane < 32 && wave >= 2) {
    #pragma unroll
    for (int q = 0; q < 81; ++q) sm_red[((wave - 2) * 32 + c) * 81 + q] += O[q];
  }
  __syncthreads();
  // final O = sm_red[0][c][*] + sm_red[1][c][*]

  // ---------------- build cat (aggregate-CG | identity | power-CG) ----------------
  {
    constexpr int colL[31]   = {0,0,0,0,0,0,0, 1,1,1,1,1,1,1,1,1,1,1, 2,2,2,2,2,2,2,2,2,2,2,2,2};
    constexpr int colKind[31]= {0,0,0,1,2,2,2, 0,0,0,0,0,1,2,2,2,2,2, 0,0,0,0,0,0,1,2,2,2,2,2,2};
    constexpr int colL1[31]  = {0,1,2,0,0,1,2, 0,1,1,1,2,0,0,1,1,1,2, 0,1,1,2,2,2,0,0,1,1,2,2,2};
    constexpr int colL2[31]  = {0,1,2,0,0,1,2, 1,0,1,2,1,0,1,0,1,2,1, 2,1,2,0,1,2,0,2,1,2,0,1,2};
    constexpr int colCg[31]  = {0,1,10,0,0,1,10, 35,44,53,80,125,0,35,44,53,80,125,
                                170,195,240,315,340,415,0,170,195,240,315,340,415};
    constexpr int colP[31]   = {0,1,2,3,4,5,6, 0,1,2,3,4,5,6,7,8,9,10, 0,1,2,3,4,5,6,7,8,9,10,11,12};
    constexpr int DD[3]      = {1,3,5};
    constexpr int catBase[3] = {0,224,1280};
    constexpr int aOff[3]    = {0,1,4};
    constexpr int oOff[9]    = {0,1,4, 9,12,21, 36,41,56}; // (l1*3+l2) -> O offset

    for (int col = g; col < 31; col += 8) {
      const int l = colL[col];
      const int d = DD[l];
      const int kind = colKind[col];
      float* catp = &sm_cat[catBase[l] + (colP[col] * CC + c) * d];
      if (kind == 1) {            // identity
        for (int z = 0; z < d; ++z) catp[z] = sm_ai[c * 9 + aOff[l] + z];
      } else if (kind == 0) {     // aggregate: contract O with cg
        const int l1 = colL1[col], l2 = colL2[col];
        const int d12 = DD[l1] * DD[l2];
        const float* cgp = &sm_cg[colCg[col]];
        const float* r0 = &sm_red[c * 81 + oOff[l1 * 3 + l2]];
        const float* r1 = r0 + 32 * 81;
        for (int z = 0; z < d; ++z) {
          float s = 0.f;
          for (int q = 0; q < d12; ++q) s += (r0[q] + r1[q]) * cgp[q * d + z];
          catp[z] = s;
        }
      } else {                    // power: atom_i x atom_i with cg
        const int l1 = colL1[col], l2 = colL2[col];
        const int d1 = DD[l1], d2 = DD[l2];
        const float* cgp = &sm_cg[colCg[col]];
        const float* a1p = &sm_ai[c * 9 + aOff[l1]];
        const float* a2p = &sm_ai[c * 9 + aOff[l2]];
        for (int z = 0; z < d; ++z) {
          float s = 0.f;
          for (int x = 0; x < d1; ++x)
            for (int y = 0; y < d2; ++y) s += a1p[x] * a2p[y] * cgp[(x * d2 + y) * d + z];
          catp[z] = s;
        }
      }
    }
  }
  __syncthreads();

  // ---------------- channel mix: out[l][co][z] = sum_k cat_l[k][z] * w_l[k][co] ----------------
  float* mixp = sm_red;  // reuse (needs 8*288 = 2304 floats)
  {
    float acc[9];
    #pragma unroll
    for (int q = 0; q < 9; ++q) acc[q] = 0.f;
    const int co = c;
    for (int k = g; k < 224; k += 8)
      acc[0] += sm_cat[k] * p.w0[k * CC + co];
    for (int k = g; k < 352; k += 8) {
      float wv = p.w1[k * CC + co];
      acc[1] += sm_cat[224 + k * 3 + 0] * wv;
      acc[2] += sm_cat[224 + k * 3 + 1] * wv;
      acc[3] += sm_cat[224 + k * 3 + 2] * wv;
    }
    for (int k = g; k < 416; k += 8) {
      float wv = p.w2[k * CC + co];
      #pragma unroll
      for (int z = 0; z < 5; ++z) acc[4 + z] += sm_cat[1280 + k * 5 + z] * wv;
    }
    #pragma unroll
    for (int q = 0; q < 9; ++q) mixp[g * 288 + co * 9 + q] = acc[q];
  }
  __syncthreads();

  // ---------------- final partial-sum + store ----------------
  const int outNodeBase = (b * NN + i) * CC;
  for (int s2 = tid; s2 < 288; s2 += 256) {
    float v = 0.f;
    #pragma unroll
    for (int gg = 0; gg < 8; ++gg) v += mixp[gg * 288 + s2];
    const int co = s2 / 9, zz = s2 - co * 9;
    int oidx;
    if (zz == 0)     oidx = outNodeBase + co;                              // l=0
    else if (zz < 4) oidx = 32768  + (outNodeBase + co) * 3 + (zz - 1);    // l=1
    else             oidx = 131072 + (outNodeBase + co) * 5 + (zz - 4);    // l=2
    p.out[oidx] = v;
  }
}

extern "C" void kernel_launch(void* const* d_in, const int* in_sizes, int n_in,
                              void* d_out, int out_size, void* d_ws, size_t ws_size,
                              hipStream_t stream) {
  Params p;
  // setup_inputs() dict order interleaves atom_l/edge_l; detect via sizes.
  const bool interleaved = (in_sizes[1] == BB * NN * NN * CC); // edge_0 at slot 1?
  if (interleaved) {
    p.atom0 = (const float*)d_in[0]; p.edge0 = (const float*)d_in[1];
    p.atom1 = (const float*)d_in[2]; p.edge1 = (const float*)d_in[3];
    p.atom2 = (const float*)d_in[4]; p.edge2 = (const float*)d_in[5];
  } else {
    p.atom0 = (const float*)d_in[0]; p.atom1 = (const float*)d_in[1]; p.atom2 = (const float*)d_in[2];
    p.edge0 = (const float*)d_in[3]; p.edge1 = (const float*)d_in[4]; p.edge2 = (const float*)d_in[5];
  }
  p.mask = d_in[6];
  for (int t = 0; t < 14; ++t) p.cg[t] = (const float*)d_in[7 + t];
  p.w0 = (const float*)d_in[21];
  p.w1 = (const float*)d_in[22];
  p.w2 = (const float*)d_in[23];
  p.out = (float*)d_out;

  lgn_kernel<<<dim3(BB * NN), dim3(256), 0, stream>>>(p);
}

// Round 3
// 107.386 us; speedup vs baseline: 1.0398x; 1.0398x over previous
//
#include <hip/hip_runtime.h>

#define BB 8
#define NN 128
#define CC 32

// O accumulator layout (81 floats per channel):
// O00:0, O01:1..3, O02:4..8, O10:9..11, O11:12..20, O12:21..35,
// O20:36..40, O21:41..55, O22:56..80

struct ParamsA {
  const float* atom0; const float* atom1; const float* atom2;
  const float* edge0; const float* edge1; const float* edge2;
  const void*  mask;
  const float* cg[14];
  float* ws;   // [node][half][48*32] aggregated cat columns
};

struct ParamsB {
  const float* atom0; const float* atom1; const float* atom2;
  const float* cg[14];
  const float* w0; const float* w1; const float* w2;
  const float* ws;
  float* out;
};

// ---------------- Kernel A: masked neighbor aggregation (partial, per j-half) ----------------
__global__ __launch_bounds__(256) void lgn_partial(ParamsA p) {
  const int tid  = threadIdx.x;
  const int c    = tid & 31;
  const int g    = tid >> 5;          // j-slot 0..7
  const int blk  = blockIdx.x;
  const int b    = blk & 7;           // XCD-friendly
  const int half = (blk >> 3) & 1;
  const int i    = blk >> 4;

  __shared__ float sm_O[32 * 81];
  __shared__ float sm_cg[540];
  __shared__ int   sm_list[64];
  __shared__ float sm_wt[64];
  __shared__ int   sm_nact, sm_mode;

  // ---- probe mask dtype (block-uniform) ----
  if (tid == 0) sm_mode = 0;
  __syncthreads();
  if (tid < 64) {
    unsigned v = ((const unsigned*)p.mask)[tid];
    if (v == 0x3F800000u) atomicOr(&sm_mode, 2);   // float32
    else if (v > 1u)      atomicOr(&sm_mode, 1);   // packed bytes
  }
  // ---- stage cg ----
  {
    constexpr int CGSZ[14] = {1,9,25, 9,9,27,45,45, 25,45,75,25,75,125};
    constexpr int CGOF[14] = {0,1,10, 35,44,53,80,125, 170,195,240,315,340,415};
    #pragma unroll
    for (int tnum = 0; tnum < 14; ++tnum)
      for (int idx = tid; idx < CGSZ[tnum]; idx += 256)
        sm_cg[CGOF[tnum] + idx] = p.cg[tnum][idx];
  }
  __syncthreads();
  const int mode = (sm_mode & 2) ? 2 : sm_mode;

  // ---- compact active-j list via ballot (wave 0) ----
  if (tid < 64) {
    const int jg   = half * 64 + tid;
    const int midx = (b * NN + i) * NN + jg;
    bool mv;
    if (mode == 0)      mv = ((const int*)p.mask)[midx] != 0;
    else if (mode == 2) mv = ((const float*)p.mask)[midx] != 0.f;
    else                mv = ((const unsigned char*)p.mask)[midx] != 0;
    unsigned long long bal = __ballot(mv);
    int pos = __popcll(bal & ((1ull << tid) - 1ull));
    if (mv) sm_list[pos] = jg;
    if (tid == 0) sm_nact = (int)__popcll(bal);
  }
  __syncthreads();
  const int nact = sm_nact;
  const int nt   = (nact + 7) >> 3;
  if (tid < 64) {
    sm_wt[tid] = (tid < nact) ? 1.f : 0.f;
    if (tid >= nact && tid < nt * 8 && nact > 0) sm_list[tid] = sm_list[0];
  }
  __syncthreads();

  // ---- branch-free pipelined neighbor loop ----
  float O[81];
  #pragma unroll
  for (int q = 0; q < 81; ++q) O[q] = 0.f;

  const float* a0b = p.atom0 +  b * NN * CC + c;
  const float* a1b = p.atom1 + (b * NN * CC + c) * 3;
  const float* a2b = p.atom2 + (b * NN * CC + c) * 5;
  const float* e0b = p.edge0 +  ((b * NN + i) * NN) * CC + c;
  const float* e1b = p.edge1 + (((b * NN + i) * NN) * CC + c) * 3;
  const float* e2b = p.edge2 + (((b * NN + i) * NN) * CC + c) * 5;

  for (int t = 0; t < nt; ++t) {
    const int   k  = t * 8 + g;
    const int   j  = sm_list[k];
    const float wt = sm_wt[k];
    const float* a1p = a1b + j * CC * 3;
    const float* a2p = a2b + j * CC * 5;
    const float* e1p = e1b + j * CC * 3;
    const float* e2p = e2b + j * CC * 5;
    const float a0 = a0b[j * CC];
    const float e0 = e0b[j * CC] * wt;
    float a1v[3], e1v[3], a2v[5], e2v[5];
    #pragma unroll
    for (int x = 0; x < 3; ++x) { a1v[x] = a1p[x]; e1v[x] = e1p[x] * wt; }
    #pragma unroll
    for (int x = 0; x < 5; ++x) { a2v[x] = a2p[x]; e2v[x] = e2p[x] * wt; }

    O[0] += a0 * e0;
    #pragma unroll
    for (int y = 0; y < 3; ++y) O[1 + y] += a0 * e1v[y];
    #pragma unroll
    for (int y = 0; y < 5; ++y) O[4 + y] += a0 * e2v[y];
    #pragma unroll
    for (int x = 0; x < 3; ++x) O[9 + x] += a1v[x] * e0;
    #pragma unroll
    for (int x = 0; x < 3; ++x)
      #pragma unroll
      for (int y = 0; y < 3; ++y) O[12 + x * 3 + y] += a1v[x] * e1v[y];
    #pragma unroll
    for (int x = 0; x < 3; ++x)
      #pragma unroll
      for (int y = 0; y < 5; ++y) O[21 + x * 5 + y] += a1v[x] * e2v[y];
    #pragma unroll
    for (int x = 0; x < 5; ++x) O[36 + x] += a2v[x] * e0;
    #pragma unroll
    for (int x = 0; x < 5; ++x)
      #pragma unroll
      for (int y = 0; y < 3; ++y) O[41 + x * 3 + y] += a2v[x] * e1v[y];
    #pragma unroll
    for (int x = 0; x < 5; ++x)
      #pragma unroll
      for (int y = 0; y < 5; ++y) O[56 + x * 5 + y] += a2v[x] * e2v[y];
  }

  // ---- reduce 8 j-slots: shfl within wave, serialized LDS adds across waves ----
  #pragma unroll
  for (int q = 0; q < 81; ++q) O[q] += __shfl_down(O[q], 32);

  const int wave = tid >> 6;
  const int lane = tid & 63;
  if (wave == 0 && lane < 32) {
    #pragma unroll
    for (int q = 0; q < 81; ++q) sm_O[c * 81 + q] = O[q];
  }
  __syncthreads();
  if (wave == 1 && lane < 32) {
    #pragma unroll
    for (int q = 0; q < 81; ++q) sm_O[c * 81 + q] += O[q];
  }
  __syncthreads();
  if (wave == 2 && lane < 32) {
    #pragma unroll
    for (int q = 0; q < 81; ++q) sm_O[c * 81 + q] += O[q];
  }
  __syncthreads();
  if (wave == 3 && lane < 32) {
    #pragma unroll
    for (int q = 0; q < 81; ++q) sm_O[c * 81 + q] += O[q];
  }
  __syncthreads();

  // ---- contract O with CG -> 48 aggregated floats per channel, store to ws ----
  {
    constexpr int aggD[14]   = {1,1,1, 3,3,3,3,3, 5,5,5,5,5,5};
    constexpr int aggD12[14] = {1,9,25, 3,3,9,15,15, 5,9,15,5,15,25};
    constexpr int aggCg[14]  = {0,1,10, 35,44,53,80,125, 170,195,240,315,340,415};
    constexpr int aggO[14]   = {0,12,56, 1,9,12,21,41, 4,12,21,36,41,56};
    constexpr int aggF[14]   = {0,1,2, 3,6,9,12,15, 18,23,28,33,38,43};
    const long wsbase = (long)(((b * NN + i) * 2 + half)) * 1536;
    for (int col = g; col < 14; col += 8) {
      const int d = aggD[col], d12 = aggD12[col], f0 = aggF[col];
      const float* cgp = &sm_cg[aggCg[col]];
      const float* Op  = &sm_O[c * 81 + aggO[col]];
      for (int z = 0; z < d; ++z) {
        float s = 0.f;
        for (int q = 0; q < d12; ++q) s += Op[q] * cgp[q * d + z];
        p.ws[wsbase + (f0 + z) * 32 + c] = s;
      }
    }
  }
}

// ---------------- Kernel B: cat assembly (agg|identity|power) + channel mix ----------------
__global__ __launch_bounds__(256) void lgn_final(ParamsB p) {
  const int tid = threadIdx.x;
  const int c   = tid & 31;
  const int g   = tid >> 5;
  const int blk = blockIdx.x;
  const int b   = blk & 7;
  const int i   = blk >> 3;
  const int node = b * NN + i;

  __shared__ float sm_cat[3360];
  __shared__ float sm_cg[540];
  __shared__ float sm_ai[288];
  __shared__ float sm_mix[2304];

  // ---- stage cg + node atoms ----
  {
    constexpr int CGSZ[14] = {1,9,25, 9,9,27,45,45, 25,45,75,25,75,125};
    constexpr int CGOF[14] = {0,1,10, 35,44,53,80,125, 170,195,240,315,340,415};
    #pragma unroll
    for (int tnum = 0; tnum < 14; ++tnum)
      for (int idx = tid; idx < CGSZ[tnum]; idx += 256)
        sm_cg[CGOF[tnum] + idx] = p.cg[tnum][idx];
    const int nodeBase = node * CC;
    for (int s2 = tid; s2 < 288; s2 += 256) {
      int cc = s2 / 9, comp = s2 - cc * 9;
      float v;
      if (comp == 0)      v = p.atom0[nodeBase + cc];
      else if (comp < 4)  v = p.atom1[(nodeBase + cc) * 3 + comp - 1];
      else                v = p.atom2[(nodeBase + cc) * 5 + comp - 4];
      sm_ai[s2] = v;
    }
  }
  __syncthreads();

  const float* wsA = p.ws + (long)(node * 2 + 0) * 1536;
  const float* wsB = p.ws + (long)(node * 2 + 1) * 1536;

  // ---- build cat ----
  {
    constexpr int colL[31]   = {0,0,0,0,0,0,0, 1,1,1,1,1,1,1,1,1,1,1, 2,2,2,2,2,2,2,2,2,2,2,2,2};
    constexpr int colKind[31]= {0,0,0,1,2,2,2, 0,0,0,0,0,1,2,2,2,2,2, 0,0,0,0,0,0,1,2,2,2,2,2,2};
    constexpr int colL1[31]  = {0,1,2,0,0,1,2, 0,1,1,1,2,0,0,1,1,1,2, 0,1,1,2,2,2,0,0,1,1,2,2,2};
    constexpr int colL2[31]  = {0,1,2,0,0,1,2, 1,0,1,2,1,0,1,0,1,2,1, 2,1,2,0,1,2,0,2,1,2,0,1,2};
    constexpr int colCg[31]  = {0,1,10,0,0,1,10, 35,44,53,80,125,0,35,44,53,80,125,
                                170,195,240,315,340,415,0,170,195,240,315,340,415};
    constexpr int colP[31]   = {0,1,2,3,4,5,6, 0,1,2,3,4,5,6,7,8,9,10, 0,1,2,3,4,5,6,7,8,9,10,11,12};
    constexpr int colF[31]   = {0,1,2,-1,-1,-1,-1, 3,6,9,12,15,-1,-1,-1,-1,-1,-1,
                                18,23,28,33,38,43,-1,-1,-1,-1,-1,-1,-1};
    constexpr int DD[3]      = {1,3,5};
    constexpr int catBase[3] = {0,224,1280};
    constexpr int aOff[3]    = {0,1,4};

    for (int col = g; col < 31; col += 8) {
      const int l = colL[col];
      const int d = DD[l];
      const int kind = colKind[col];
      float* catp = &sm_cat[catBase[l] + (colP[col] * CC + c) * d];
      if (kind == 0) {            // aggregate: staged partials from ws
        const int f0 = colF[col];
        for (int z = 0; z < d; ++z)
          catp[z] = wsA[(f0 + z) * 32 + c] + wsB[(f0 + z) * 32 + c];
      } else if (kind == 1) {     // identity
        for (int z = 0; z < d; ++z) catp[z] = sm_ai[c * 9 + aOff[l] + z];
      } else {                    // power
        const int l1 = colL1[col], l2 = colL2[col];
        const int d1 = DD[l1], d2 = DD[l2];
        const float* cgp = &sm_cg[colCg[col]];
        const float* a1p = &sm_ai[c * 9 + aOff[l1]];
        const float* a2p = &sm_ai[c * 9 + aOff[l2]];
        for (int z = 0; z < d; ++z) {
          float s = 0.f;
          for (int x = 0; x < d1; ++x)
            for (int y = 0; y < d2; ++y) s += a1p[x] * a2p[y] * cgp[(x * d2 + y) * d + z];
          catp[z] = s;
        }
      }
    }
  }
  __syncthreads();

  // ---- channel mix ----
  {
    float acc[9];
    #pragma unroll
    for (int q = 0; q < 9; ++q) acc[q] = 0.f;
    const int co = c;
    for (int k = g; k < 224; k += 8)
      acc[0] += sm_cat[k] * p.w0[k * CC + co];
    for (int k = g; k < 352; k += 8) {
      float wv = p.w1[k * CC + co];
      acc[1] += sm_cat[224 + k * 3 + 0] * wv;
      acc[2] += sm_cat[224 + k * 3 + 1] * wv;
      acc[3] += sm_cat[224 + k * 3 + 2] * wv;
    }
    for (int k = g; k < 416; k += 8) {
      float wv = p.w2[k * CC + co];
      #pragma unroll
      for (int z = 0; z < 5; ++z) acc[4 + z] += sm_cat[1280 + k * 5 + z] * wv;
    }
    #pragma unroll
    for (int q = 0; q < 9; ++q) sm_mix[g * 288 + co * 9 + q] = acc[q];
  }
  __syncthreads();

  // ---- final partial-sum + store ----
  const int outNodeBase = node * CC;
  for (int s2 = tid; s2 < 288; s2 += 256) {
    float v = 0.f;
    #pragma unroll
    for (int gg = 0; gg < 8; ++gg) v += sm_mix[gg * 288 + s2];
    const int co = s2 / 9, zz = s2 - co * 9;
    int oidx;
    if (zz == 0)     oidx = outNodeBase + co;                              // l=0
    else if (zz < 4) oidx = 32768  + (outNodeBase + co) * 3 + (zz - 1);    // l=1
    else             oidx = 131072 + (outNodeBase + co) * 5 + (zz - 4);    // l=2
    p.out[oidx] = v;
  }
}

extern "C" void kernel_launch(void* const* d_in, const int* in_sizes, int n_in,
                              void* d_out, int out_size, void* d_ws, size_t ws_size,
                              hipStream_t stream) {
  const float *atom0, *atom1, *atom2, *edge0, *edge1, *edge2;
  const bool interleaved = (in_sizes[1] == BB * NN * NN * CC);
  if (interleaved) {
    atom0 = (const float*)d_in[0]; edge0 = (const float*)d_in[1];
    atom1 = (const float*)d_in[2]; edge1 = (const float*)d_in[3];
    atom2 = (const float*)d_in[4]; edge2 = (const float*)d_in[5];
  } else {
    atom0 = (const float*)d_in[0]; atom1 = (const float*)d_in[1]; atom2 = (const float*)d_in[2];
    edge0 = (const float*)d_in[3]; edge1 = (const float*)d_in[4]; edge2 = (const float*)d_in[5];
  }

  ParamsA pa;
  pa.atom0 = atom0; pa.atom1 = atom1; pa.atom2 = atom2;
  pa.edge0 = edge0; pa.edge1 = edge1; pa.edge2 = edge2;
  pa.mask  = d_in[6];
  for (int t = 0; t < 14; ++t) pa.cg[t] = (const float*)d_in[7 + t];
  pa.ws = (float*)d_ws;

  ParamsB pb;
  pb.atom0 = atom0; pb.atom1 = atom1; pb.atom2 = atom2;
  for (int t = 0; t < 14; ++t) pb.cg[t] = (const float*)d_in[7 + t];
  pb.w0 = (const float*)d_in[21];
  pb.w1 = (const float*)d_in[22];
  pb.w2 = (const float*)d_in[23];
  pb.ws = (const float*)d_ws;
  pb.out = (float*)d_out;

  lgn_partial<<<dim3(BB * NN * 2), dim3(256), 0, stream>>>(pa);
  lgn_final<<<dim3(BB * NN), dim3(256), 0, stream>>>(pb);
}

// Round 4
// 87.668 us; speedup vs baseline: 1.2736x; 1.2249x over previous
//
#include <hip/hip_runtime.h>

#define BB 8
#define NN 128
#define CC 32

struct Params {
  const float* __restrict__ atom0; const float* __restrict__ atom1; const float* __restrict__ atom2;
  const float* __restrict__ edge0; const float* __restrict__ edge1; const float* __restrict__ edge2;
  const void*  mask;
  const float* __restrict__ cg[14];
  const float* __restrict__ w0; const float* __restrict__ w1; const float* __restrict__ w2;
  float* __restrict__ out;
};

// Fused single kernel: block = (b,i), 512 threads = 32 c x 16 slots.
// slot s: sx = s>>3 (wave-uniform: waves 0-3 do x-rows 0..3, waves 4-7 rows 4..8),
//         jp = s&7 (j-slot). O[x][y] accumulated flat (x*9+y).
__global__ __launch_bounds__(512, 4) void lgn_fused(Params p) {
  const int tid = threadIdx.x;
  const int c   = tid & 31;
  const int s   = tid >> 5;      // 0..15
  const int sx  = s >> 3;        // wave-uniform
  const int jp  = s & 7;
  const int blk = blockIdx.x;
  const int b   = blk & 7;       // XCD-friendly
  const int i   = blk >> 3;

  // phase1: two reduce slabs @ [0..5759] (slab = 45q x 64col)
  // phase2: O flat [0..2591] | cat [2592..5951] | mix [5952..8255]
  __shared__ float sm_big[8256];
  __shared__ float sm_cg[540];
  __shared__ float sm_ai[288];
  __shared__ int   sm_list[128];
  __shared__ int   sm_nact, sm_mode;

  // ---- probe mask dtype ----
  if (tid == 0) sm_mode = 0;
  __syncthreads();
  if (tid < 64) {
    unsigned v = ((const unsigned*)p.mask)[tid];
    if (v == 0x3F800000u) atomicOr(&sm_mode, 2);   // float32
    else if (v > 1u)      atomicOr(&sm_mode, 1);   // packed bytes
  }
  // ---- stage cg + node-i atoms ----
  {
    constexpr int CGSZ[14] = {1,9,25, 9,9,27,45,45, 25,45,75,25,75,125};
    constexpr int CGOF[14] = {0,1,10, 35,44,53,80,125, 170,195,240,315,340,415};
    #pragma unroll
    for (int t = 0; t < 14; ++t)
      for (int idx = tid; idx < CGSZ[t]; idx += 512)
        sm_cg[CGOF[t] + idx] = p.cg[t][idx];
    const int nodeBase = (b * NN + i) * CC;
    for (int s2 = tid; s2 < 288; s2 += 512) {
      int cc = s2 / 9, comp = s2 - cc * 9;
      float v;
      if (comp == 0)      v = p.atom0[nodeBase + cc];
      else if (comp < 4)  v = p.atom1[(nodeBase + cc) * 3 + comp - 1];
      else                v = p.atom2[(nodeBase + cc) * 5 + comp - 4];
      sm_ai[s2] = v;
    }
  }
  __syncthreads();
  const int mode = (sm_mode & 2) ? 2 : sm_mode;

  // ---- ballot compaction of full 128-j row (wave 0) ----
  if (tid < 64) {
    const int row = (b * NN + i) * NN;
    bool mv0, mv1;
    if (mode == 0) {
      mv0 = ((const int*)p.mask)[row + tid] != 0;
      mv1 = ((const int*)p.mask)[row + tid + 64] != 0;
    } else if (mode == 2) {
      mv0 = ((const float*)p.mask)[row + tid] != 0.f;
      mv1 = ((const float*)p.mask)[row + tid + 64] != 0.f;
    } else {
      mv0 = ((const unsigned char*)p.mask)[row + tid] != 0;
      mv1 = ((const unsigned char*)p.mask)[row + tid + 64] != 0;
    }
    unsigned long long b0 = __ballot(mv0);
    unsigned long long b1 = __ballot(mv1);
    int n0 = (int)__popcll(b0);
    unsigned long long lt = (1ull << tid) - 1ull;
    if (mv0) sm_list[__popcll(b0 & lt)] = tid;
    if (mv1) sm_list[n0 + __popcll(b1 & lt)] = tid + 64;
    if (tid == 0) sm_nact = n0 + (int)__popcll(b1);
  }
  __syncthreads();
  const int nact = sm_nact;
  const int nt   = (nact + 7) >> 3;

  // ---- main neighbor loop: 45 (or 36) accumulators/thread ----
  float acc[5][9];
  #pragma unroll
  for (int k = 0; k < 5; ++k)
    #pragma unroll
    for (int y = 0; y < 9; ++y) acc[k][y] = 0.f;

  const float* e0b = p.edge0 + ((long)(b * NN + i) * NN) * CC + c;
  const float* e1b = p.edge1 + (((long)(b * NN + i) * NN) * CC + c) * 3;
  const float* e2b = p.edge2 + (((long)(b * NN + i) * NN) * CC + c) * 5;
  const float* a0b = p.atom0 +  b * NN * CC + c;
  const float* a1b = p.atom1 + (b * NN * CC + c) * 3;
  const float* a2b = p.atom2 + (b * NN * CC + c) * 5;

  for (int t = 0; t < nt; ++t) {
    const int idx = t * 8 + jp;
    const int j   = sm_list[idx < nact ? idx : 0];
    const float wt = (idx < nact) ? 1.f : 0.f;
    float e[9], a[5];
    e[0] = e0b[j * 32];
    const float* e1p = e1b + j * 96;
    const float* e2p = e2b + j * 160;
    #pragma unroll
    for (int y = 0; y < 3; ++y) e[1 + y] = e1p[y];
    #pragma unroll
    for (int y = 0; y < 5; ++y) e[4 + y] = e2p[y];
    if (sx == 0) {                      // wave-uniform branch
      a[0] = a0b[j * 32] * wt;
      const float* a1p = a1b + j * 96;
      #pragma unroll
      for (int k = 0; k < 3; ++k) a[1 + k] = a1p[k] * wt;
      #pragma unroll
      for (int k = 0; k < 4; ++k)
        #pragma unroll
        for (int y = 0; y < 9; ++y) acc[k][y] += a[k] * e[y];
    } else {
      const float* a2p = a2b + j * 160;
      #pragma unroll
      for (int k = 0; k < 5; ++k) a[k] = a2p[k] * wt;
      #pragma unroll
      for (int k = 0; k < 5; ++k)
        #pragma unroll
        for (int y = 0; y < 9; ++y) acc[k][y] += a[k] * e[y];
    }
  }

  // ---- tree reduce 8 jp-slots (2 slabs of 45x64) ----
  const int sc = sx * 32 + c;
  // r1: jp 6,7 write; jp 4,5 add
  if (jp >= 6) {
    float* sp = &sm_big[(jp - 6) * 2880 + sc];
    #pragma unroll
    for (int k = 0; k < 5; ++k)
      #pragma unroll
      for (int y = 0; y < 9; ++y) sp[(k * 9 + y) * 64] = acc[k][y];
  }
  __syncthreads();
  if (jp == 4 || jp == 5) {
    const float* sp = &sm_big[(jp - 4) * 2880 + sc];
    #pragma unroll
    for (int k = 0; k < 5; ++k)
      #pragma unroll
      for (int y = 0; y < 9; ++y) acc[k][y] += sp[(k * 9 + y) * 64];
  }
  __syncthreads();
  // r2: jp 4,5 write; jp 0,1 add
  if (jp == 4 || jp == 5) {
    float* sp = &sm_big[(jp - 4) * 2880 + sc];
    #pragma unroll
    for (int k = 0; k < 5; ++k)
      #pragma unroll
      for (int y = 0; y < 9; ++y) sp[(k * 9 + y) * 64] = acc[k][y];
  }
  __syncthreads();
  if (jp <= 1) {
    const float* sp = &sm_big[jp * 2880 + sc];
    #pragma unroll
    for (int k = 0; k < 5; ++k)
      #pragma unroll
      for (int y = 0; y < 9; ++y) acc[k][y] += sp[(k * 9 + y) * 64];
  }
  __syncthreads();
  // r3: jp 2,3 write; jp 0,1 add
  if (jp == 2 || jp == 3) {
    float* sp = &sm_big[(jp - 2) * 2880 + sc];
    #pragma unroll
    for (int k = 0; k < 5; ++k)
      #pragma unroll
      for (int y = 0; y < 9; ++y) sp[(k * 9 + y) * 64] = acc[k][y];
  }
  __syncthreads();
  if (jp <= 1) {
    const float* sp = &sm_big[jp * 2880 + sc];
    #pragma unroll
    for (int k = 0; k < 5; ++k)
      #pragma unroll
      for (int y = 0; y < 9; ++y) acc[k][y] += sp[(k * 9 + y) * 64];
  }
  // r4: jp0 += jp1 (lanes 0..31 <- 32..63 within waves 0 and 4)
  #pragma unroll
  for (int k = 0; k < 5; ++k)
    #pragma unroll
    for (int y = 0; y < 9; ++y) acc[k][y] += __shfl_down(acc[k][y], 32);
  __syncthreads();   // all slab reads done before O overwrites region

  // ---- write final O flat [c][x*9+y] at sm_big[0..2591] ----
  if (s == 0) {
    #pragma unroll
    for (int k = 0; k < 4; ++k)
      #pragma unroll
      for (int y = 0; y < 9; ++y) sm_big[c * 81 + k * 9 + y] = acc[k][y];
  } else if (s == 8) {
    #pragma unroll
    for (int k = 0; k < 5; ++k)
      #pragma unroll
      for (int y = 0; y < 9; ++y) sm_big[c * 81 + (4 + k) * 9 + y] = acc[k][y];
  }
  __syncthreads();

  // ---- build cat (aggregate | identity | power) at sm_big[2592..] ----
  {
    constexpr int colL[31]   = {0,0,0,0,0,0,0, 1,1,1,1,1,1,1,1,1,1,1, 2,2,2,2,2,2,2,2,2,2,2,2,2};
    constexpr int colKind[31]= {0,0,0,1,2,2,2, 0,0,0,0,0,1,2,2,2,2,2, 0,0,0,0,0,0,1,2,2,2,2,2,2};
    constexpr int colL1[31]  = {0,1,2,0,0,1,2, 0,1,1,1,2,0,0,1,1,1,2, 0,1,1,2,2,2,0,0,1,1,2,2,2};
    constexpr int colL2[31]  = {0,1,2,0,0,1,2, 1,0,1,2,1,0,1,0,1,2,1, 2,1,2,0,1,2,0,2,1,2,0,1,2};
    constexpr int colCg[31]  = {0,1,10,0,0,1,10, 35,44,53,80,125,0,35,44,53,80,125,
                                170,195,240,315,340,415,0,170,195,240,315,340,415};
    constexpr int colP[31]   = {0,1,2,3,4,5,6, 0,1,2,3,4,5,6,7,8,9,10, 0,1,2,3,4,5,6,7,8,9,10,11,12};
    constexpr int DD[3]      = {1,3,5};
    constexpr int catBase[3] = {0,224,1280};
    constexpr int aOff[3]    = {0,1,4};

    for (int col = s; col < 31; col += 16) {
      const int l = colL[col];
      const int d = DD[l];
      const int kind = colKind[col];
      float* catp = &sm_big[2592 + catBase[l] + (colP[col] * CC + c) * d];
      if (kind == 1) {            // identity
        for (int z = 0; z < d; ++z) catp[z] = sm_ai[c * 9 + aOff[l] + z];
      } else if (kind == 0) {     // aggregate: contract O(flat x*9+y) with cg
        const int l1 = colL1[col], l2 = colL2[col];
        const int d1 = DD[l1], d2 = DD[l2];
        const int x0 = aOff[l1], y0 = aOff[l2];
        const float* cgp = &sm_cg[colCg[col]];
        const float* Ofl = &sm_big[c * 81];
        for (int z = 0; z < d; ++z) {
          float sum = 0.f;
          for (int xi = 0; xi < d1; ++xi)
            for (int yi = 0; yi < d2; ++yi)
              sum += Ofl[(x0 + xi) * 9 + y0 + yi] * cgp[(xi * d2 + yi) * d + z];
          catp[z] = sum;
        }
      } else {                    // power: atom_i x atom_i
        const int l1 = colL1[col], l2 = colL2[col];
        const int d1 = DD[l1], d2 = DD[l2];
        const float* cgp = &sm_cg[colCg[col]];
        const float* a1p = &sm_ai[c * 9 + aOff[l1]];
        const float* a2p = &sm_ai[c * 9 + aOff[l2]];
        for (int z = 0; z < d; ++z) {
          float sum = 0.f;
          for (int xi = 0; xi < d1; ++xi)
            for (int yi = 0; yi < d2; ++yi)
              sum += a1p[xi] * a2p[yi] * cgp[(xi * d2 + yi) * d + z];
          catp[z] = sum;
        }
      }
    }
  }
  __syncthreads();

  // ---- channel mix (16-way k-split, shfl pair-combine -> 8 partials) ----
  {
    float accm[9];
    #pragma unroll
    for (int q = 0; q < 9; ++q) accm[q] = 0.f;
    const int co = c;
    for (int k = s; k < 224; k += 16)
      accm[0] += sm_big[2592 + k] * p.w0[k * CC + co];
    for (int k = s; k < 352; k += 16) {
      float wv = p.w1[k * CC + co];
      accm[1] += sm_big[2592 + 224 + k * 3 + 0] * wv;
      accm[2] += sm_big[2592 + 224 + k * 3 + 1] * wv;
      accm[3] += sm_big[2592 + 224 + k * 3 + 2] * wv;
    }
    for (int k = s; k < 416; k += 16) {
      float wv = p.w2[k * CC + co];
      #pragma unroll
      for (int z = 0; z < 5; ++z)
        accm[4 + z] += sm_big[2592 + 1280 + k * 5 + z] * wv;
    }
    #pragma unroll
    for (int q = 0; q < 9; ++q) accm[q] += __shfl_down(accm[q], 32);
    if ((s & 1) == 0) {
      #pragma unroll
      for (int q = 0; q < 9; ++q)
        sm_big[5952 + (s >> 1) * 288 + co * 9 + q] = accm[q];
    }
  }
  __syncthreads();

  // ---- final partial-sum + store ----
  if (tid < 288) {
    float v = 0.f;
    #pragma unroll
    for (int gg = 0; gg < 8; ++gg) v += sm_big[5952 + gg * 288 + tid];
    const int co = tid / 9, zz = tid - co * 9;
    const int nb = (b * NN + i) * CC;
    int oidx;
    if (zz == 0)     oidx = nb + co;                          // l=0
    else if (zz < 4) oidx = 32768  + (nb + co) * 3 + (zz - 1); // l=1
    else             oidx = 131072 + (nb + co) * 5 + (zz - 4); // l=2
    p.out[oidx] = v;
  }
}

extern "C" void kernel_launch(void* const* d_in, const int* in_sizes, int n_in,
                              void* d_out, int out_size, void* d_ws, size_t ws_size,
                              hipStream_t stream) {
  Params p;
  const bool interleaved = (in_sizes[1] == BB * NN * NN * CC);
  if (interleaved) {
    p.atom0 = (const float*)d_in[0]; p.edge0 = (const float*)d_in[1];
    p.atom1 = (const float*)d_in[2]; p.edge1 = (const float*)d_in[3];
    p.atom2 = (const float*)d_in[4]; p.edge2 = (const float*)d_in[5];
  } else {
    p.atom0 = (const float*)d_in[0]; p.atom1 = (const float*)d_in[1]; p.atom2 = (const float*)d_in[2];
    p.edge0 = (const float*)d_in[3]; p.edge1 = (const float*)d_in[4]; p.edge2 = (const float*)d_in[5];
  }
  p.mask = d_in[6];
  for (int t = 0; t < 14; ++t) p.cg[t] = (const float*)d_in[7 + t];
  p.w0 = (const float*)d_in[21];
  p.w1 = (const float*)d_in[22];
  p.w2 = (const float*)d_in[23];
  p.out = (float*)d_out;

  lgn_fused<<<dim3(BB * NN), dim3(512), 0, stream>>>(p);
}